// Round 6
// baseline (100.744 us; speedup 1.0000x reference)
//
#include <hip/hip_runtime.h>

#define I_DIM 128
#define H_DIM 64
#define BATCH 8
#define SEQ   4096
#define NBIN  (SEQ/2 + 1)     // 2049 bins of the 4096-rfft (K_hat)
#define NBIN2 (SEQ + 1)       // 4097 bins of the 8192-rfft (Kf)

// LDS swizzle on complex (8B) indices: spreads strided Stockham accesses
// across bank-pairs.
#define SZ(a) ((a) ^ (((a) >> 4) & 15))

// Module-scope device scratch (graph-capture safe, fully rewritten per call).
__device__ float2 g_Kf[I_DIM * NBIN2];   // rfft_8192(K_pad) [i][m], ~4.2 MB

__device__ inline float2 cmul(float2 a, float2 b) {
    return make_float2(a.x * b.x - a.y * b.y, a.x * b.y + a.y * b.x);
}
__device__ inline float2 cadd(float2 a, float2 b) { return make_float2(a.x + b.x, a.y + b.y); }
__device__ inline float2 csub(float2 a, float2 b) { return make_float2(a.x - b.x, a.y - b.y); }

// DFT8 (DIF network), natural-order outputs b[k] = sum_j a[j] W8^{jk}.
__device__ inline void dft8(float2 a[8]) {
    const float C = 0.70710678118654752f;
    float2 s0 = cadd(a[0], a[4]), s1 = cadd(a[1], a[5]);
    float2 s2 = cadd(a[2], a[6]), s3 = cadd(a[3], a[7]);
    float2 d0 = csub(a[0], a[4]), d1 = csub(a[1], a[5]);
    float2 d2 = csub(a[2], a[6]), d3 = csub(a[3], a[7]);
    d1 = make_float2(C * (d1.x + d1.y), C * (d1.y - d1.x));   // * W8^1
    d2 = make_float2(d2.y, -d2.x);                            // * W8^2 = -i
    d3 = make_float2(C * (d3.y - d3.x), -C * (d3.x + d3.y));  // * W8^3
    {
        float2 p0 = cadd(s0, s2), p1 = cadd(s1, s3);
        float2 m0 = csub(s0, s2), m1 = csub(s1, s3);
        m1 = make_float2(m1.y, -m1.x);
        a[0] = cadd(p0, p1); a[4] = csub(p0, p1);
        a[2] = cadd(m0, m1); a[6] = csub(m0, m1);
    }
    {
        float2 p0 = cadd(d0, d2), p1 = cadd(d1, d3);
        float2 m0 = csub(d0, d2), m1 = csub(d1, d3);
        m1 = make_float2(m1.y, -m1.x);
        a[1] = cadd(p0, p1); a[5] = csub(p0, p1);
        a[3] = cadd(m0, m1); a[7] = csub(m0, m1);
    }
}

__device__ inline void dft4(float2 a[4]) {
    float2 p0 = cadd(a[0], a[2]), p1 = cadd(a[1], a[3]);
    float2 m0 = csub(a[0], a[2]), m1 = csub(a[1], a[3]);
    m1 = make_float2(m1.y, -m1.x);
    a[0] = cadd(p0, p1); a[2] = csub(p0, p1);
    a[1] = cadd(m0, m1); a[3] = csub(m0, m1);
}

// ---------------------------------------------------------------------------
// Radix-8 Stockham DIF stage (single FFT, NT threads) — as verified r3-r5.
// ---------------------------------------------------------------------------
template <int N, int S, int NT>
__device__ inline void stage8(float2* __restrict__ lds, int tid) {
    constexpr int NB = N / 8;
    constexpr int ITER = (NB + NT - 1) / NT;
    const bool act = (NB >= NT) || (tid < NB);
    float2 d[ITER][8];
#pragma unroll
    for (int b = 0; b < ITER; ++b) {
        const int u = tid + b * NT;
        if (act) {
#pragma unroll
            for (int j = 0; j < 8; ++j)
                d[b][j] = lds[SZ(u + NB * j)];
        }
    }
    __syncthreads();
#pragma unroll
    for (int b = 0; b < ITER; ++b) {
        const int u = tid + b * NT;
        if (act) {
            const int q = u & (S - 1);
            dft8(d[b]);
            if constexpr (S < NB) {
                const float cang = (float)(-6.283185307179586) / (float)N;
                float sn, cs;
                __sincosf(cang * (float)(u - q), &sn, &cs);
                const float2 w = make_float2(cs, sn);
                float2 t = w;
#pragma unroll
                for (int k = 1; k < 8; ++k) {
                    d[b][k] = cmul(d[b][k], t);
                    if (k < 7) t = cmul(t, w);
                }
            }
            const int base = 8 * u - 7 * q;
#pragma unroll
            for (int k = 0; k < 8; ++k)
                lds[SZ(base + k * S)] = d[b][k];
        }
    }
    __syncthreads();
}

// Radix-4 Stockham stage (mixed-radix first stage for N=2048).
template <int N, int S, int NT>
__device__ inline void stage4(float2* __restrict__ lds, int tid) {
    constexpr int NB = N / 4;
    constexpr int ITER = (NB + NT - 1) / NT;
    const bool act = (NB >= NT) || (tid < NB);
    float2 d[ITER][4];
#pragma unroll
    for (int b = 0; b < ITER; ++b) {
        const int u = tid + b * NT;
        if (act) {
#pragma unroll
            for (int j = 0; j < 4; ++j)
                d[b][j] = lds[SZ(u + NB * j)];
        }
    }
    __syncthreads();
#pragma unroll
    for (int b = 0; b < ITER; ++b) {
        const int u = tid + b * NT;
        if (act) {
            const int q = u & (S - 1);
            dft4(d[b]);
            if constexpr (S < NB) {
                const float cang = (float)(-6.283185307179586) / (float)N;
                float sn, cs;
                __sincosf(cang * (float)(u - q), &sn, &cs);
                const float2 w = make_float2(cs, sn);
                float2 t = w;
#pragma unroll
                for (int k = 1; k < 4; ++k) {
                    d[b][k] = cmul(d[b][k], t);
                    if (k < 3) t = cmul(t, w);
                }
            }
            const int base = 4 * u - 3 * q;
#pragma unroll
            for (int k = 0; k < 4; ++k)
                lds[SZ(base + k * S)] = d[b][k];
        }
    }
    __syncthreads();
}

// ---------------------------------------------------------------------------
// Dual-FFT radix-8 stage: one butterfly of FFT-A and one of FFT-B per thread
// between a single barrier pair. Twiddle factors computed ONCE, shared.
// N = 4096, NT = 512 (NB == NT, exact fit).
// ---------------------------------------------------------------------------
template <int N, int S>
__device__ inline void stage8x2(float2* __restrict__ A, float2* __restrict__ B,
                                int tid) {
    constexpr int NB = N / 8;     // 512
    float2 da[8], db[8];
#pragma unroll
    for (int j = 0; j < 8; ++j) da[j] = A[SZ(tid + NB * j)];
#pragma unroll
    for (int j = 0; j < 8; ++j) db[j] = B[SZ(tid + NB * j)];
    __syncthreads();

    const int u = tid;
    const int q = u & (S - 1);
    const int base = 8 * u - 7 * q;

    float2 tw[7];
    if constexpr (S < NB) {
        const float cang = (float)(-6.283185307179586) / (float)N;
        float sn, cs;
        __sincosf(cang * (float)(u - q), &sn, &cs);
        tw[0] = make_float2(cs, sn);
#pragma unroll
        for (int k = 1; k < 7; ++k) tw[k] = cmul(tw[k - 1], tw[0]);
    }

    dft8(da);
    if constexpr (S < NB) {
#pragma unroll
        for (int k = 1; k < 8; ++k) da[k] = cmul(da[k], tw[k - 1]);
    }
#pragma unroll
    for (int k = 0; k < 8; ++k) A[SZ(base + k * S)] = da[k];

    dft8(db);
    if constexpr (S < NB) {
#pragma unroll
        for (int k = 1; k < 8; ++k) db[k] = cmul(db[k], tw[k - 1]);
    }
#pragma unroll
    for (int k = 0; k < 8; ++k) B[SZ(base + k * S)] = db[k];

    __syncthreads();
}

// ---------------------------------------------------------------------------
// Kernel 1 (merged khat+kprep), one block per channel i, 512 threads.
//   phase 0: H[i, 0..2048] -> LDS  (the Cauchy low-rank frequency response)
//   phase 1: icfft_2048 (half-size pack, conj trick; radix 4*8*8*8)
//   phase 2: v-pack -> cfft_4096 (radix 8^4) -> untwist -> Kf
// ---------------------------------------------------------------------------
__global__ __launch_bounds__(512) void kprep_kernel(const float* __restrict__ Bm,
                                                    const float* __restrict__ Cm,
                                                    const float* __restrict__ Lm,
                                                    const float* __restrict__ Pm,
                                                    const float* __restrict__ Qm) {
    __shared__ float2 lds[4096];
    __shared__ float2 sH[NBIN];
    const int tid = threadIdx.x;
    const int i = blockIdx.x;

    // ---- phase 0: khat row i ----
    {
        const float* Brow = Bm + i * H_DIM;
        const float* Crow = Cm + i * H_DIM;
        const float* Lrow = Lm + i * H_DIM;
        const float* Prow = Pm + i * H_DIM;
        const float* Qrow = Qm + i * H_DIM;
        for (int k = tid; k < NBIN; k += 512) {
            float theta = (float)(6.283185307179586 / (double)SEQ) * (float)k;
            float sn, cs;
            sincosf(theta, &sn, &cs);
            float tr = 1.0f - cs, ti = -sn;
            float br = 1.0f + cs, bi = sn;
            float idn = 1.0f / (br * br + bi * bi);
            float gr = 20.0f * (tr * br + ti * bi) * idn;
            float gi = 20.0f * (ti * br - tr * bi) * idn;
            float cr = 2.0f * br * idn;
            float ci = -2.0f * bi * idn;

            float k00r = 0.f, k00i = 0.f, k01r = 0.f, k01i = 0.f;
            float k10r = 0.f, k10i = 0.f, k11r = 0.f, k11i = 0.f;
#pragma unroll 8
            for (int h = 0; h < H_DIM; ++h) {
                float lam = Lrow[h];
                float dr = gr - lam;
                float di = gi;
                float im = 1.0f / (dr * dr + di * di);
                float ivr = dr * im;
                float ivi = -di * im;
                float bv = Brow[h], cv = Crow[h], pv = Prow[h], qv = Qrow[h];
                float cb = cv * bv;
                float cp = cv * pv;
                float qb = qv * bv;
                float qp = qv * pv;
                k00r += cb * ivr; k00i += cb * ivi;
                k01r += cp * ivr; k01i += cp * ivi;
                k10r += qb * ivr; k10i += qb * ivi;
                k11r += qp * ivr; k11i += qp * ivi;
            }
            float t1r = 1.0f + k11r, t1i = k11i;
            float t2r = k01r * t1r - k01i * t1i;
            float t2i = k01r * t1i + k01i * t1r;
            float t3r = t2r * k10r - t2i * k10i;
            float t3i = t2r * k10i + t2i * k10r;
            float nr = k00r - t3r, ni = k00i - t3i;
            sH[k] = make_float2(cr * nr - ci * ni, cr * ni + ci * nr);
        }
    }
    __syncthreads();

    // ---- phase 1: icfft_2048 via half-size pack + conj trick ----
#pragma unroll
    for (int r = 0; r < 4; ++r) {
        int m = tid + (r << 9);          // m < 2048
        float2 Hm = sH[m];
        float2 Hc = sH[2048 - m];
        float pr = Hm.x + Hc.x, pi2 = Hm.y - Hc.y;
        float dr = Hm.x - Hc.x, di = Hm.y + Hc.y;
        float sn, cs;
        __sincosf((float)(3.141592653589793 / 2048.0) * (float)m, &sn, &cs);
        float Or = 0.5f * (cs * dr - sn * di);
        float Oi = 0.5f * (sn * dr + cs * di);
        lds[SZ(m)] = make_float2(0.5f * pr - Oi, -(0.5f * pi2 + Or));
    }
    __syncthreads();

    stage4<2048, 1,   512>(lds, tid);
    stage8<2048, 4,   512>(lds, tid);
    stage8<2048, 32,  512>(lds, tid);
    stage8<2048, 256, 512>(lds, tid);    // S == N/8: twiddle-free

    // v[n] = K[2n] + j*K[2n+1] = conj(out[n])/2048; zero-pad top half.
    const float s1 = 1.0f / 2048.0f;
#pragma unroll
    for (int r = 0; r < 4; ++r) {
        int n = tid + (r << 9);
        float2 o = lds[SZ(n)];
        lds[SZ(n)]        = make_float2(o.x * s1, -o.y * s1);
        lds[SZ(n + 2048)] = make_float2(0.f, 0.f);
    }
    __syncthreads();

    stage8<4096, 1,   512>(lds, tid);
    stage8<4096, 8,   512>(lds, tid);
    stage8<4096, 64,  512>(lds, tid);
    stage8<4096, 512, 512>(lds, tid);

    // untwist: Kf[m] = E - (j/2) e^{-j*pi*m/4096} (Zv[m]-conj(Zv[4096-m]))
    float2* Kfrow = g_Kf + (size_t)i * NBIN2;
#pragma unroll
    for (int r = 0; r < 9; ++r) {
        int m = tid + (r << 9);
        if (m <= 4096) {
            float2 Zq = lds[SZ(m & 4095)];
            float2 Zr = lds[SZ((4096 - m) & 4095)];
            float sn, cs;
            __sincosf((float)(-3.141592653589793 / 4096.0) * (float)m, &sn, &cs);
            float pr = Zq.x + Zr.x, pi2 = Zq.y - Zr.y;
            float dr = Zq.x - Zr.x, di = Zq.y + Zr.y;
            float jt_r = -sn * dr - cs * di;
            float jt_i =  cs * dr - sn * di;
            Kfrow[m] = make_float2(0.5f * (pr - jt_r), 0.5f * (pi2 - jt_i));
        }
    }
}

// ---------------------------------------------------------------------------
// Kernel 2: FFT convolution, TWO channels (i0, i0+64) of one batch per block.
// 512 threads, single-buffer-per-FFT (2 x 32 KB LDS), dual-butterfly stages.
// b = blockIdx&7 keeps each batch's x-column traffic on one XCD's L2.
// ---------------------------------------------------------------------------
__device__ inline void combine_pair(float2* __restrict__ lds,
                                    const float2* __restrict__ Kfrow,
                                    int m, bool write_partner) {
    float2 Zq = lds[SZ(m & 4095)];
    float2 Zr = lds[SZ((4096 - m) & 4095)];
    float sn, cs;
    __sincosf((float)(-3.141592653589793 / 4096.0) * (float)m, &sn, &cs);
    float pr = Zq.x + Zr.x, pi2 = Zq.y - Zr.y;
    float dr = Zq.x - Zr.x, di = Zq.y + Zr.y;
    float jt_r = -sn * dr - cs * di;
    float jt_i =  cs * dr - sn * di;
    float2 Xm  = make_float2(0.5f * (pr - jt_r),  0.5f * ( pi2 - jt_i));
    float2 Xm2 = make_float2(0.5f * (pr + jt_r),  0.5f * (-pi2 - jt_i));
    float2 Ym  = cmul(Xm,  Kfrow[m]);
    float2 Ym2 = cmul(Xm2, Kfrow[4096 - m]);
    float qr = Ym.x + Ym2.x, qi = Ym.y - Ym2.y;
    float er = Ym.x - Ym2.x, ei = Ym.y + Ym2.y;
    float gr2 = sn * er - cs * ei;
    float gi2 = sn * ei + cs * er;
    // store conj(Zy) for the conj-trick inverse
    lds[SZ(m & 4095)] = make_float2(0.5f * (qr + gr2), -0.5f * (qi + gi2));
    if (write_partner)
        lds[SZ(4096 - m)] = make_float2(0.5f * (qr - gr2), 0.5f * (qi - gi2));
}

__global__ __launch_bounds__(512) void fftconv_kernel(const float* __restrict__ x,
                                                      float* __restrict__ y) {
    __shared__ float2 ldsA[4096];
    __shared__ float2 ldsB[4096];
    const int tid = threadIdx.x;
    const int b  = blockIdx.x & 7;
    const int i0 = blockIdx.x >> 3;      // 0..63
    const int i1 = i0 + 64;

    const float* xbA = x + (size_t)b * SEQ * I_DIM + i0;
    const float* xbB = x + (size_t)b * SEQ * I_DIM + i1;
#pragma unroll
    for (int r = 0; r < 4; ++r) {
        int n = tid + (r << 9);          // n < 2048
        float reA = xbA[(size_t)(2 * n) * I_DIM];
        float imA = xbA[(size_t)(2 * n + 1) * I_DIM];
        float reB = xbB[(size_t)(2 * n) * I_DIM];
        float imB = xbB[(size_t)(2 * n + 1) * I_DIM];
        ldsA[SZ(n)]        = make_float2(reA, imA);
        ldsA[SZ(n + 2048)] = make_float2(0.f, 0.f);
        ldsB[SZ(n)]        = make_float2(reB, imB);
        ldsB[SZ(n + 2048)] = make_float2(0.f, 0.f);
    }
    __syncthreads();

    stage8x2<4096, 1>(ldsA, ldsB, tid);
    stage8x2<4096, 8>(ldsA, ldsB, tid);
    stage8x2<4096, 64>(ldsA, ldsB, tid);
    stage8x2<4096, 512>(ldsA, ldsB, tid);

    // combine: thread owns slot-pairs {m, 4096-m}; no internal barrier.
    const float2* KfA = g_Kf + (size_t)i0 * NBIN2;
    const float2* KfB = g_Kf + (size_t)i1 * NBIN2;
#pragma unroll
    for (int r = 0; r < 4; ++r) {
        int m = tid + (r << 9);          // 0..2047
        combine_pair(ldsA, KfA, m, m != 0);
        combine_pair(ldsB, KfB, m, m != 0);
    }
    if (tid == 0) {
        combine_pair(ldsA, KfA, 2048, false);   // self-paired Nyquist bin
        combine_pair(ldsB, KfB, 2048, false);
    }
    __syncthreads();

    stage8x2<4096, 1>(ldsA, ldsB, tid);
    stage8x2<4096, 8>(ldsA, ldsB, tid);
    stage8x2<4096, 64>(ldsA, ldsB, tid);
    stage8x2<4096, 512>(ldsA, ldsB, tid);

    const float inv = 1.0f / 4096.0f;
    float* ybA = y + (size_t)b * SEQ * I_DIM + i0;
    float* ybB = y + (size_t)b * SEQ * I_DIM + i1;
#pragma unroll
    for (int r = 0; r < 4; ++r) {
        int n = tid + (r << 9);          // n < 2048
        float2 vA = ldsA[SZ(n)];
        float2 vB = ldsB[SZ(n)];
        ybA[(size_t)(2 * n) * I_DIM]     = vA.x * inv;
        ybA[(size_t)(2 * n + 1) * I_DIM] = -vA.y * inv;
        ybB[(size_t)(2 * n) * I_DIM]     = vB.x * inv;
        ybB[(size_t)(2 * n + 1) * I_DIM] = -vB.y * inv;
    }
}

// ---------------------------------------------------------------------------
extern "C" void kernel_launch(void* const* d_in, const int* in_sizes, int n_in,
                              void* d_out, int out_size, void* d_ws, size_t ws_size,
                              hipStream_t stream) {
    const float* x  = (const float*)d_in[0];
    const float* Bm = (const float*)d_in[1];
    const float* Cm = (const float*)d_in[2];
    const float* Lm = (const float*)d_in[3];
    const float* Pm = (const float*)d_in[4];
    const float* Qm = (const float*)d_in[5];
    float* out = (float*)d_out;

    kprep_kernel<<<I_DIM, 512, 0, stream>>>(Bm, Cm, Lm, Pm, Qm);
    fftconv_kernel<<<BATCH * I_DIM / 2, 512, 0, stream>>>(x, out);
}

// Round 7
// 98.879 us; speedup vs baseline: 1.0189x; 1.0189x over previous
//
#include <hip/hip_runtime.h>

#define I_DIM 128
#define H_DIM 64
#define BATCH 8
#define SEQ   4096
#define NBIN  (SEQ/2 + 1)     // 2049 bins of the 4096-rfft (K_hat)
#define NBIN2 (SEQ + 1)       // 4097 bins of the 8192-rfft (Kf)

// LDS swizzle for the kprep Stockham core (proven r3-r5).
#define SZ(a) ((a) ^ (((a) >> 4) & 15))
// Row-padded flat addressing for the fftconv 64x64 matrix: index m in [0,4096).
#define AD(m) ((((m) >> 6) * 65) + ((m) & 63))

// Module-scope device scratch (graph-capture safe, fully rewritten per call).
__device__ float2 g_Hh[I_DIM * NBIN];    // K_hat  [i][k], ~2.1 MB
__device__ float2 g_Kf[I_DIM * NBIN2];   // rfft_8192(K_pad) [i][m], ~4.2 MB

__device__ inline float2 cmul(float2 a, float2 b) {
    return make_float2(a.x * b.x - a.y * b.y, a.x * b.y + a.y * b.x);
}
__device__ inline float2 cadd(float2 a, float2 b) { return make_float2(a.x + b.x, a.y + b.y); }
__device__ inline float2 csub(float2 a, float2 b) { return make_float2(a.x - b.x, a.y - b.y); }

// ===========================================================================
// kprep machinery (radix-8 LDS Stockham) — VERBATIM from the passing round 5.
// ===========================================================================
__device__ inline void dft8(float2 a[8]) {
    const float C = 0.70710678118654752f;
    float2 s0 = cadd(a[0], a[4]), s1 = cadd(a[1], a[5]);
    float2 s2 = cadd(a[2], a[6]), s3 = cadd(a[3], a[7]);
    float2 d0 = csub(a[0], a[4]), d1 = csub(a[1], a[5]);
    float2 d2 = csub(a[2], a[6]), d3 = csub(a[3], a[7]);
    d1 = make_float2(C * (d1.x + d1.y), C * (d1.y - d1.x));   // * W8^1
    d2 = make_float2(d2.y, -d2.x);                            // * W8^2 = -i
    d3 = make_float2(C * (d3.y - d3.x), -C * (d3.x + d3.y));  // * W8^3
    {
        float2 p0 = cadd(s0, s2), p1 = cadd(s1, s3);
        float2 m0 = csub(s0, s2), m1 = csub(s1, s3);
        m1 = make_float2(m1.y, -m1.x);
        a[0] = cadd(p0, p1); a[4] = csub(p0, p1);
        a[2] = cadd(m0, m1); a[6] = csub(m0, m1);
    }
    {
        float2 p0 = cadd(d0, d2), p1 = cadd(d1, d3);
        float2 m0 = csub(d0, d2), m1 = csub(d1, d3);
        m1 = make_float2(m1.y, -m1.x);
        a[1] = cadd(p0, p1); a[5] = csub(p0, p1);
        a[3] = cadd(m0, m1); a[7] = csub(m0, m1);
    }
}

__device__ inline void dft4(float2 a[4]) {
    float2 p0 = cadd(a[0], a[2]), p1 = cadd(a[1], a[3]);
    float2 m0 = csub(a[0], a[2]), m1 = csub(a[1], a[3]);
    m1 = make_float2(m1.y, -m1.x);
    a[0] = cadd(p0, p1); a[2] = csub(p0, p1);
    a[1] = cadd(m0, m1); a[3] = csub(m0, m1);
}

template <int N, int S, int NT>
__device__ inline void stage8(float2* __restrict__ lds, int tid) {
    constexpr int NB = N / 8;
    constexpr int ITER = (NB + NT - 1) / NT;
    const bool act = (NB >= NT) || (tid < NB);
    float2 d[ITER][8];
#pragma unroll
    for (int b = 0; b < ITER; ++b) {
        const int u = tid + b * NT;
        if (act) {
#pragma unroll
            for (int j = 0; j < 8; ++j)
                d[b][j] = lds[SZ(u + NB * j)];
        }
    }
    __syncthreads();
#pragma unroll
    for (int b = 0; b < ITER; ++b) {
        const int u = tid + b * NT;
        if (act) {
            const int q = u & (S - 1);
            dft8(d[b]);
            if constexpr (S < NB) {
                const float cang = (float)(-6.283185307179586) / (float)N;
                float sn, cs;
                __sincosf(cang * (float)(u - q), &sn, &cs);
                const float2 w = make_float2(cs, sn);
                float2 t = w;
#pragma unroll
                for (int k = 1; k < 8; ++k) {
                    d[b][k] = cmul(d[b][k], t);
                    if (k < 7) t = cmul(t, w);
                }
            }
            const int base = 8 * u - 7 * q;
#pragma unroll
            for (int k = 0; k < 8; ++k)
                lds[SZ(base + k * S)] = d[b][k];
        }
    }
    __syncthreads();
}

template <int N, int S, int NT>
__device__ inline void stage4(float2* __restrict__ lds, int tid) {
    constexpr int NB = N / 4;
    constexpr int ITER = (NB + NT - 1) / NT;
    const bool act = (NB >= NT) || (tid < NB);
    float2 d[ITER][4];
#pragma unroll
    for (int b = 0; b < ITER; ++b) {
        const int u = tid + b * NT;
        if (act) {
#pragma unroll
            for (int j = 0; j < 4; ++j)
                d[b][j] = lds[SZ(u + NB * j)];
        }
    }
    __syncthreads();
#pragma unroll
    for (int b = 0; b < ITER; ++b) {
        const int u = tid + b * NT;
        if (act) {
            const int q = u & (S - 1);
            dft4(d[b]);
            if constexpr (S < NB) {
                const float cang = (float)(-6.283185307179586) / (float)N;
                float sn, cs;
                __sincosf(cang * (float)(u - q), &sn, &cs);
                const float2 w = make_float2(cs, sn);
                float2 t = w;
#pragma unroll
                for (int k = 1; k < 4; ++k) {
                    d[b][k] = cmul(d[b][k], t);
                    if (k < 3) t = cmul(t, w);
                }
            }
            const int base = 4 * u - 3 * q;
#pragma unroll
            for (int k = 0; k < 4; ++k)
                lds[SZ(base + k * S)] = d[b][k];
        }
    }
    __syncthreads();
}

// ---------------------------------------------------------------------------
// Kernel 1: K_hat[i,k] — verbatim from round 5 (big grid, fills the GPU).
// ---------------------------------------------------------------------------
__global__ void khat_kernel(const float* __restrict__ Bm,
                            const float* __restrict__ Cm,
                            const float* __restrict__ Lm,
                            const float* __restrict__ Pm,
                            const float* __restrict__ Qm) {
    int k = blockIdx.x * blockDim.x + threadIdx.x;
    int i = blockIdx.y;
    if (k >= NBIN) return;

    float theta = (float)(6.283185307179586 / (double)SEQ) * (float)k;
    float sn, cs;
    sincosf(theta, &sn, &cs);

    float tr = 1.0f - cs, ti = -sn;
    float br = 1.0f + cs, bi = sn;
    float idn = 1.0f / (br * br + bi * bi);
    float gr = 20.0f * (tr * br + ti * bi) * idn;
    float gi = 20.0f * (ti * br - tr * bi) * idn;
    float cr = 2.0f * br * idn;
    float ci = -2.0f * bi * idn;

    const float* Brow = Bm + i * H_DIM;
    const float* Crow = Cm + i * H_DIM;
    const float* Lrow = Lm + i * H_DIM;
    const float* Prow = Pm + i * H_DIM;
    const float* Qrow = Qm + i * H_DIM;

    float k00r = 0.f, k00i = 0.f, k01r = 0.f, k01i = 0.f;
    float k10r = 0.f, k10i = 0.f, k11r = 0.f, k11i = 0.f;

#pragma unroll 8
    for (int h = 0; h < H_DIM; ++h) {
        float lam = Lrow[h];
        float dr = gr - lam;
        float di = gi;
        float im = 1.0f / (dr * dr + di * di);
        float ivr = dr * im;
        float ivi = -di * im;
        float bv = Brow[h], cv = Crow[h], pv = Prow[h], qv = Qrow[h];
        float cb = cv * bv;
        float cp = cv * pv;
        float qb = qv * bv;
        float qp = qv * pv;
        k00r += cb * ivr; k00i += cb * ivi;
        k01r += cp * ivr; k01i += cp * ivi;
        k10r += qb * ivr; k10i += qb * ivi;
        k11r += qp * ivr; k11i += qp * ivi;
    }

    float t1r = 1.0f + k11r, t1i = k11i;
    float t2r = k01r * t1r - k01i * t1i;
    float t2i = k01r * t1i + k01i * t1r;
    float t3r = t2r * k10r - t2i * k10i;
    float t3i = t2r * k10i + t2i * k10r;
    float nr = k00r - t3r, ni = k00i - t3i;
    g_Hh[(size_t)i * NBIN + k] = make_float2(cr * nr - ci * ni, cr * ni + ci * nr);
}

// ---------------------------------------------------------------------------
// Kernel 2: K-prep — verbatim from round 5 (proven).
// ---------------------------------------------------------------------------
__global__ __launch_bounds__(512) void kprep_kernel() {
    __shared__ float2 lds[4096];
    const int tid = threadIdx.x;
    const int i = blockIdx.x;
    const float2* Hrow = g_Hh + (size_t)i * NBIN;

#pragma unroll
    for (int r = 0; r < 4; ++r) {
        int m = tid + (r << 9);          // m < 2048
        float2 Hm = Hrow[m];
        float2 Hc = Hrow[2048 - m];
        float pr = Hm.x + Hc.x, pi2 = Hm.y - Hc.y;
        float dr = Hm.x - Hc.x, di = Hm.y + Hc.y;
        float sn, cs;
        __sincosf((float)(3.141592653589793 / 2048.0) * (float)m, &sn, &cs);
        float Or = 0.5f * (cs * dr - sn * di);
        float Oi = 0.5f * (sn * dr + cs * di);
        lds[SZ(m)] = make_float2(0.5f * pr - Oi, -(0.5f * pi2 + Or));
    }
    __syncthreads();

    stage4<2048, 1,   512>(lds, tid);
    stage8<2048, 4,   512>(lds, tid);
    stage8<2048, 32,  512>(lds, tid);
    stage8<2048, 256, 512>(lds, tid);

    const float s1 = 1.0f / 2048.0f;
#pragma unroll
    for (int r = 0; r < 4; ++r) {
        int n = tid + (r << 9);
        float2 o = lds[SZ(n)];
        lds[SZ(n)]        = make_float2(o.x * s1, -o.y * s1);
        lds[SZ(n + 2048)] = make_float2(0.f, 0.f);
    }
    __syncthreads();

    stage8<4096, 1,   512>(lds, tid);
    stage8<4096, 8,   512>(lds, tid);
    stage8<4096, 64,  512>(lds, tid);
    stage8<4096, 512, 512>(lds, tid);

    float2* Kfrow = g_Kf + (size_t)i * NBIN2;
#pragma unroll
    for (int r = 0; r < 9; ++r) {
        int m = tid + (r << 9);
        if (m <= 4096) {
            float2 Zq = lds[SZ(m & 4095)];
            float2 Zr = lds[SZ((4096 - m) & 4095)];
            float sn, cs;
            __sincosf((float)(-3.141592653589793 / 4096.0) * (float)m, &sn, &cs);
            float pr = Zq.x + Zr.x, pi2 = Zq.y - Zr.y;
            float dr = Zq.x - Zr.x, di = Zq.y + Zr.y;
            float jt_r = -sn * dr - cs * di;
            float jt_i =  cs * dr - sn * di;
            Kfrow[m] = make_float2(0.5f * (pr - jt_r), 0.5f * (pi2 - jt_i));
        }
    }
}

// ===========================================================================
// Kernel 3: FFT convolution — four-step 64x64, wave-shuffle 64-pt FFTs.
// One (b,i) per block, 512 threads (8 waves x 8 columns), 9 barriers total.
//
// Lane-FFT (radix-2 DIF across 64 lanes, verified by hand on N=4):
//   stage s: half = 32>>s; partner p = shfl_xor(v, half);
//   lower (lane&half==0): v' = v + p
//   upper:                v' = (p - v) * W_{2*half}^{lane & (half-1)}
// Output: lane l holds X[brev6(l)].
// Four-step (verified algebraically):
//   z[64*n1+n2] -> FFT over n1 (cols) -> * W4096^{n2*k1} -> transpose
//   -> FFT over n2 -> X[k1 + 64*k2].
// ===========================================================================
__device__ inline void lanefft64(float2 v[8], int lane) {
#pragma unroll
    for (int s = 0; s < 6; ++s) {
        const int half = 32 >> s;
        const bool up = (lane & half) != 0;
        float2 w = make_float2(1.f, 0.f);
        if (half > 1) {
            float ang = (float)(-3.141592653589793) * (float)(lane & (half - 1)) / (float)half;
            __sincosf(ang, &w.y, &w.x);
        }
#pragma unroll
        for (int j = 0; j < 8; ++j) {
            float px = __shfl_xor(v[j].x, half);
            float py = __shfl_xor(v[j].y, half);
            float2 p  = make_float2(px, py);
            float2 sm = cadd(v[j], p);
            float2 df = csub(p, v[j]);
            float2 dw = (half > 1) ? cmul(df, w) : df;
            v[j] = up ? dw : sm;
        }
    }
}

__device__ inline void combine_pair_pad(float2* __restrict__ M,
                                        const float2* __restrict__ Kfrow,
                                        int m, bool write_partner) {
    float2 Zq = M[AD(m & 4095)];
    float2 Zr = M[AD((4096 - m) & 4095)];
    float sn, cs;
    __sincosf((float)(-3.141592653589793 / 4096.0) * (float)m, &sn, &cs);
    float pr = Zq.x + Zr.x, pi2 = Zq.y - Zr.y;
    float dr = Zq.x - Zr.x, di = Zq.y + Zr.y;
    float jt_r = -sn * dr - cs * di;
    float jt_i =  cs * dr - sn * di;
    float2 Xm  = make_float2(0.5f * (pr - jt_r),  0.5f * ( pi2 - jt_i));
    float2 Xm2 = make_float2(0.5f * (pr + jt_r),  0.5f * (-pi2 - jt_i));
    float2 Ym  = cmul(Xm,  Kfrow[m]);
    float2 Ym2 = cmul(Xm2, Kfrow[4096 - m]);
    float qr = Ym.x + Ym2.x, qi = Ym.y - Ym2.y;
    float er = Ym.x - Ym2.x, ei = Ym.y + Ym2.y;
    float gr2 = sn * er - cs * ei;
    float gi2 = sn * ei + cs * er;
    // store conj(Zy) for the conj-trick inverse
    M[AD(m & 4095)] = make_float2(0.5f * (qr + gr2), -0.5f * (qi + gi2));
    if (write_partner)
        M[AD(4096 - m)] = make_float2(0.5f * (qr - gr2), 0.5f * (qi - gi2));
}

__global__ __launch_bounds__(512) void fftconv_kernel(const float* __restrict__ x,
                                                      float* __restrict__ y) {
    __shared__ float2 M[64 * 65];        // 33,280 B, row-padded 64x64
    const int tid  = threadIdx.x;
    const int lane = tid & 63;
    const int wv   = tid >> 6;           // 0..7
    const int b = blockIdx.x & 7;
    const int i = blockIdx.x >> 3;
    const float cang4096 = (float)(-6.283185307179586 / 4096.0);
    const int k1rev = (int)(__brev((unsigned)lane) >> 26);   // brev6(lane)

    // ---- pack: z[n] = x[2n] + j*x[2n+1]  (n<2048), rows 32..63 zero ----
    const float* xb = x + (size_t)b * SEQ * I_DIM + i;
#pragma unroll
    for (int r = 0; r < 4; ++r) {
        int n = tid + (r << 9);          // n < 2048; row = n>>6 in [0,32)
        float re = xb[(size_t)(2 * n) * I_DIM];
        float im = xb[(size_t)(2 * n + 1) * I_DIM];
        M[(n >> 6) * 65 + (n & 63)] = make_float2(re, im);
        M[(32 + (n >> 6)) * 65 + (n & 63)] = make_float2(0.f, 0.f);
    }
    __syncthreads();

    float2 v[8];

    // ================= forward cfft4096 =================
    // pass 1: FFT over n1 (rows) for each column c
#pragma unroll
    for (int j = 0; j < 8; ++j) v[j] = M[lane * 65 + (wv * 8 + j)];
    __syncthreads();
    lanefft64(v, lane);
#pragma unroll
    for (int j = 0; j < 8; ++j) {
        int c = wv * 8 + j;
        float sn, cs;
        __sincosf(cang4096 * (float)(c * k1rev), &sn, &cs);
        v[j] = cmul(v[j], make_float2(cs, sn));
        M[c * 65 + k1rev] = v[j];        // transposed: row=n2(c), col=k1
    }
    __syncthreads();

    // pass 2: FFT over n2 for each k1 column
#pragma unroll
    for (int j = 0; j < 8; ++j) v[j] = M[lane * 65 + (wv * 8 + j)];
    __syncthreads();
    lanefft64(v, lane);
#pragma unroll
    for (int j = 0; j < 8; ++j) {
        // lane holds X[k1 + 64*k2], k1 = c = wv*8+j, k2 = brev6(lane)
        M[k1rev * 65 + (wv * 8 + j)] = v[j];   // store at m = k1 + 64*k2
    }
    __syncthreads();

    // ================= combine with Kf =================
    const float2* Kfrow = g_Kf + (size_t)i * NBIN2;
#pragma unroll
    for (int r = 0; r < 4; ++r) {
        int m = tid + (r << 9);          // 0..2047
        combine_pair_pad(M, Kfrow, m, m != 0);
    }
    if (tid == 0)
        combine_pair_pad(M, Kfrow, 2048, false);
    __syncthreads();

    // ================= inverse (conj trick: data is conj'd) =================
    // pass 1
#pragma unroll
    for (int j = 0; j < 8; ++j) v[j] = M[lane * 65 + (wv * 8 + j)];
    __syncthreads();
    lanefft64(v, lane);
#pragma unroll
    for (int j = 0; j < 8; ++j) {
        int c = wv * 8 + j;
        float sn, cs;
        __sincosf(cang4096 * (float)(c * k1rev), &sn, &cs);
        v[j] = cmul(v[j], make_float2(cs, sn));
        M[c * 65 + k1rev] = v[j];
    }
    __syncthreads();

    // pass 2
#pragma unroll
    for (int j = 0; j < 8; ++j) v[j] = M[lane * 65 + (wv * 8 + j)];
    __syncthreads();
    lanefft64(v, lane);

    // unpack + store: w[k], k = c + 64*brev6(lane); zy[k]=conj(w)/4096;
    // y[2k] = w.x/4096, y[2k+1] = -w.y/4096, valid for k < 2048.
    const float inv = 1.0f / 4096.0f;
    float* yb = y + (size_t)b * SEQ * I_DIM + i;
    if (k1rev < 32) {
#pragma unroll
        for (int j = 0; j < 8; ++j) {
            int k = (wv * 8 + j) + 64 * k1rev;
            yb[(size_t)(2 * k) * I_DIM]     = v[j].x * inv;
            yb[(size_t)(2 * k + 1) * I_DIM] = -v[j].y * inv;
        }
    }
}

// ---------------------------------------------------------------------------
extern "C" void kernel_launch(void* const* d_in, const int* in_sizes, int n_in,
                              void* d_out, int out_size, void* d_ws, size_t ws_size,
                              hipStream_t stream) {
    const float* x  = (const float*)d_in[0];
    const float* Bm = (const float*)d_in[1];
    const float* Cm = (const float*)d_in[2];
    const float* Lm = (const float*)d_in[3];
    const float* Pm = (const float*)d_in[4];
    const float* Qm = (const float*)d_in[5];
    float* out = (float*)d_out;

    khat_kernel<<<dim3((NBIN + 255) / 256, I_DIM), 256, 0, stream>>>(Bm, Cm, Lm, Pm, Qm);
    kprep_kernel<<<I_DIM, 512, 0, stream>>>();
    fftconv_kernel<<<BATCH * I_DIM, 512, 0, stream>>>(x, out);
}

// Round 8
// 77.350 us; speedup vs baseline: 1.3024x; 1.2783x over previous
//
#include <hip/hip_runtime.h>

#define I_DIM 128
#define H_DIM 64
#define BATCH 8
#define SEQ   4096
#define NBIN  (SEQ/2 + 1)     // 2049 bins of the 4096-rfft (K_hat)
#define NBIN2 (SEQ + 1)       // 4097 bins of the 8192-rfft (Kf)

// LDS swizzle (involution within 16-element chunks) — proven r3-r6.
#define SZ(a) ((a) ^ (((a) >> 4) & 15))

// Module-scope device scratch (graph-capture safe, fully rewritten per call).
__device__ float2 g_Kf[I_DIM * NBIN2];                 // ~4.2 MB
__device__ float2 g_Xf[(size_t)BATCH * I_DIM * SEQ];   // forward spectra, 33.5 MB

__device__ inline float2 cmul(float2 a, float2 b) {
    return make_float2(a.x * b.x - a.y * b.y, a.x * b.y + a.y * b.x);
}
__device__ inline float2 cadd(float2 a, float2 b) { return make_float2(a.x + b.x, a.y + b.y); }
__device__ inline float2 csub(float2 a, float2 b) { return make_float2(a.x - b.x, a.y - b.y); }

// DFT8 (DIF network), natural-order outputs b[k] = sum_j a[j] W8^{jk}.
__device__ inline void dft8(float2 a[8]) {
    const float C = 0.70710678118654752f;
    float2 s0 = cadd(a[0], a[4]), s1 = cadd(a[1], a[5]);
    float2 s2 = cadd(a[2], a[6]), s3 = cadd(a[3], a[7]);
    float2 d0 = csub(a[0], a[4]), d1 = csub(a[1], a[5]);
    float2 d2 = csub(a[2], a[6]), d3 = csub(a[3], a[7]);
    d1 = make_float2(C * (d1.x + d1.y), C * (d1.y - d1.x));   // * W8^1
    d2 = make_float2(d2.y, -d2.x);                            // * W8^2 = -i
    d3 = make_float2(C * (d3.y - d3.x), -C * (d3.x + d3.y));  // * W8^3
    {
        float2 p0 = cadd(s0, s2), p1 = cadd(s1, s3);
        float2 m0 = csub(s0, s2), m1 = csub(s1, s3);
        m1 = make_float2(m1.y, -m1.x);
        a[0] = cadd(p0, p1); a[4] = csub(p0, p1);
        a[2] = cadd(m0, m1); a[6] = csub(m0, m1);
    }
    {
        float2 p0 = cadd(d0, d2), p1 = cadd(d1, d3);
        float2 m0 = csub(d0, d2), m1 = csub(d1, d3);
        m1 = make_float2(m1.y, -m1.x);
        a[1] = cadd(p0, p1); a[5] = csub(p0, p1);
        a[3] = cadd(m0, m1); a[7] = csub(m0, m1);
    }
}

__device__ inline void dft4(float2 a[4]) {
    float2 p0 = cadd(a[0], a[2]), p1 = cadd(a[1], a[3]);
    float2 m0 = csub(a[0], a[2]), m1 = csub(a[1], a[3]);
    m1 = make_float2(m1.y, -m1.x);
    a[0] = cadd(p0, p1); a[2] = csub(p0, p1);
    a[1] = cadd(m0, m1); a[3] = csub(m0, m1);
}

// Radix-8 Stockham DIF stage (single-buffer LDS) — proven r3-r7.
template <int N, int S, int NT>
__device__ inline void stage8(float2* __restrict__ lds, int tid) {
    constexpr int NB = N / 8;
    constexpr int ITER = (NB + NT - 1) / NT;
    const bool act = (NB >= NT) || (tid < NB);
    float2 d[ITER][8];
#pragma unroll
    for (int b = 0; b < ITER; ++b) {
        const int u = tid + b * NT;
        if (act) {
#pragma unroll
            for (int j = 0; j < 8; ++j)
                d[b][j] = lds[SZ(u + NB * j)];
        }
    }
    __syncthreads();
#pragma unroll
    for (int b = 0; b < ITER; ++b) {
        const int u = tid + b * NT;
        if (act) {
            const int q = u & (S - 1);
            dft8(d[b]);
            if constexpr (S < NB) {
                const float cang = (float)(-6.283185307179586) / (float)N;
                float sn, cs;
                __sincosf(cang * (float)(u - q), &sn, &cs);
                const float2 w = make_float2(cs, sn);
                float2 t = w;
#pragma unroll
                for (int k = 1; k < 8; ++k) {
                    d[b][k] = cmul(d[b][k], t);
                    if (k < 7) t = cmul(t, w);
                }
            }
            const int base = 8 * u - 7 * q;
#pragma unroll
            for (int k = 0; k < 8; ++k)
                lds[SZ(base + k * S)] = d[b][k];
        }
    }
    __syncthreads();
}

// Radix-4 Stockham stage (mixed-radix first stage for N=2048) — proven r5.
template <int N, int S, int NT>
__device__ inline void stage4(float2* __restrict__ lds, int tid) {
    constexpr int NB = N / 4;
    constexpr int ITER = (NB + NT - 1) / NT;
    const bool act = (NB >= NT) || (tid < NB);
    float2 d[ITER][4];
#pragma unroll
    for (int b = 0; b < ITER; ++b) {
        const int u = tid + b * NT;
        if (act) {
#pragma unroll
            for (int j = 0; j < 4; ++j)
                d[b][j] = lds[SZ(u + NB * j)];
        }
    }
    __syncthreads();
#pragma unroll
    for (int b = 0; b < ITER; ++b) {
        const int u = tid + b * NT;
        if (act) {
            const int q = u & (S - 1);
            dft4(d[b]);
            if constexpr (S < NB) {
                const float cang = (float)(-6.283185307179586) / (float)N;
                float sn, cs;
                __sincosf(cang * (float)(u - q), &sn, &cs);
                const float2 w = make_float2(cs, sn);
                float2 t = w;
#pragma unroll
                for (int k = 1; k < 4; ++k) {
                    d[b][k] = cmul(d[b][k], t);
                    if (k < 3) t = cmul(t, w);
                }
            }
            const int base = 4 * u - 3 * q;
#pragma unroll
            for (int k = 0; k < 4; ++k)
                lds[SZ(base + k * S)] = d[b][k];
        }
    }
    __syncthreads();
}

// Pruned first forward stage (N=4096, S=1): top half of input is zero.
// b[2k'] = DFT4(a0..a3); b[2k'+1] = DFT4(a0, a1*W8, a2*W8^2, a3*W8^3);
// then twiddle by W4096^(u*k) (log-depth power products).
__device__ inline void stage8_first_halfzero(float2* __restrict__ lds, int tid) {
    const float C = 0.70710678118654752f;
    float2 a0 = lds[SZ(tid)];
    float2 a1 = lds[SZ(tid + 512)];
    float2 a2 = lds[SZ(tid + 1024)];
    float2 a3 = lds[SZ(tid + 1536)];
    __syncthreads();
    // even outputs
    float2 p0 = cadd(a0, a2), p1 = cadd(a1, a3);
    float2 m0 = csub(a0, a2), m1t = csub(a1, a3);
    float2 m1 = make_float2(m1t.y, -m1t.x);
    float2 b0 = cadd(p0, p1), b4 = csub(p0, p1);
    float2 b2 = cadd(m0, m1), b6 = csub(m0, m1);
    // odd outputs
    float2 c1 = make_float2(C * (a1.x + a1.y), C * (a1.y - a1.x));   // a1*W8
    float2 c2 = make_float2(a2.y, -a2.x);                            // a2*(-i)
    float2 c3 = make_float2(C * (a3.y - a3.x), -C * (a3.x + a3.y));  // a3*W8^3
    float2 q0 = cadd(a0, c2), q1 = cadd(c1, c3);
    float2 n0 = csub(a0, c2), n1t = csub(c1, c3);
    float2 n1 = make_float2(n1t.y, -n1t.x);
    float2 b1 = cadd(q0, q1), b5 = csub(q0, q1);
    float2 b3 = cadd(n0, n1), b7 = csub(n0, n1);
    // twiddles (q=0 -> w = W4096^tid), log-depth powers
    float sn, cs;
    __sincosf((float)(-6.283185307179586 / 4096.0) * (float)tid, &sn, &cs);
    float2 w1 = make_float2(cs, sn);
    float2 w2 = cmul(w1, w1), w3 = cmul(w2, w1), w4 = cmul(w2, w2);
    float2 w5 = cmul(w3, w2), w6 = cmul(w3, w3), w7 = cmul(w4, w3);
    const int base = 8 * tid;
    lds[SZ(base + 0)] = b0;
    lds[SZ(base + 1)] = cmul(b1, w1);
    lds[SZ(base + 2)] = cmul(b2, w2);
    lds[SZ(base + 3)] = cmul(b3, w3);
    lds[SZ(base + 4)] = cmul(b4, w4);
    lds[SZ(base + 5)] = cmul(b5, w5);
    lds[SZ(base + 6)] = cmul(b6, w6);
    lds[SZ(base + 7)] = cmul(b7, w7);
    __syncthreads();
}

// Pruned last inverse stage (S=512, twiddle-free): only outputs n<2048 needed.
__device__ inline void stage8_last_half(float2* __restrict__ lds, int tid) {
    float2 d[8];
#pragma unroll
    for (int j = 0; j < 8; ++j) d[j] = lds[SZ(tid + 512 * j)];
    __syncthreads();
    dft8(d);
#pragma unroll
    for (int k = 0; k < 4; ++k) lds[SZ(tid + 512 * k)] = d[k];
    __syncthreads();
}

// Combine: Zy[m] from Zx pairs {m, 4096-m} and Kf — verbatim r5 (proven).
__device__ inline void combine_pair(float2* __restrict__ lds,
                                    const float2* __restrict__ Kfrow,
                                    int m, bool write_partner) {
    float2 Zq = lds[SZ(m & 4095)];
    float2 Zr = lds[SZ((4096 - m) & 4095)];
    float sn, cs;
    __sincosf((float)(-3.141592653589793 / 4096.0) * (float)m, &sn, &cs);
    float pr = Zq.x + Zr.x, pi2 = Zq.y - Zr.y;
    float dr = Zq.x - Zr.x, di = Zq.y + Zr.y;
    float jt_r = -sn * dr - cs * di;
    float jt_i =  cs * dr - sn * di;
    float2 Xm  = make_float2(0.5f * (pr - jt_r),  0.5f * ( pi2 - jt_i));
    float2 Xm2 = make_float2(0.5f * (pr + jt_r),  0.5f * (-pi2 - jt_i));
    float2 Ym  = cmul(Xm,  Kfrow[m]);
    float2 Ym2 = cmul(Xm2, Kfrow[4096 - m]);
    float qr = Ym.x + Ym2.x, qi = Ym.y - Ym2.y;
    float er = Ym.x - Ym2.x, ei = Ym.y + Ym2.y;
    float gr2 = sn * er - cs * ei;
    float gi2 = sn * ei + cs * er;
    lds[SZ(m & 4095)] = make_float2(0.5f * (qr + gr2), -0.5f * (qi + gi2));
    if (write_partner)
        lds[SZ(4096 - m)] = make_float2(0.5f * (qr - gr2), 0.5f * (qi - gi2));
}

// ===========================================================================
// Kernel 1: blocks [0,128)  -> fused khat + kprep for channel i (32 KB LDS,
//                              H kept in-place in the FFT buffer)
//           blocks [128,1152) -> forward cfft4096 of packed x row -> g_Xf
// ===========================================================================
__global__ __launch_bounds__(512) void s4_stage1_kernel(const float* __restrict__ x,
                                                        const float* __restrict__ Bm,
                                                        const float* __restrict__ Cm,
                                                        const float* __restrict__ Lm,
                                                        const float* __restrict__ Pm,
                                                        const float* __restrict__ Qm) {
    __shared__ float2 lds[4096];
    const int tid = threadIdx.x;

    if (blockIdx.x < I_DIM) {
        // ------------------- K-chain path -------------------
        const int i = blockIdx.x;
        // phase 0: K_hat row i -> lds[k] (PLAIN index), k = 0..2048
        {
            const float* Brow = Bm + i * H_DIM;
            const float* Crow = Cm + i * H_DIM;
            const float* Lrow = Lm + i * H_DIM;
            const float* Prow = Pm + i * H_DIM;
            const float* Qrow = Qm + i * H_DIM;
            for (int k = tid; k < NBIN; k += 512) {
                float theta = (float)(6.283185307179586 / (double)SEQ) * (float)k;
                float sn, cs;
                sincosf(theta, &sn, &cs);
                float tr = 1.0f - cs, ti = -sn;
                float br = 1.0f + cs, bi = sn;
                float idn = 1.0f / (br * br + bi * bi);
                float gr = 20.0f * (tr * br + ti * bi) * idn;
                float gi = 20.0f * (ti * br - tr * bi) * idn;
                float cr = 2.0f * br * idn;
                float ci = -2.0f * bi * idn;

                float k00r = 0.f, k00i = 0.f, k01r = 0.f, k01i = 0.f;
                float k10r = 0.f, k10i = 0.f, k11r = 0.f, k11i = 0.f;
#pragma unroll 8
                for (int h = 0; h < H_DIM; ++h) {
                    float lam = Lrow[h];
                    float drr = gr - lam;
                    float dii = gi;
                    float im = 1.0f / (drr * drr + dii * dii);
                    float ivr = drr * im;
                    float ivi = -dii * im;
                    float bv = Brow[h], cv = Crow[h], pv = Prow[h], qv = Qrow[h];
                    float cb = cv * bv;
                    float cp = cv * pv;
                    float qb = qv * bv;
                    float qp = qv * pv;
                    k00r += cb * ivr; k00i += cb * ivi;
                    k01r += cp * ivr; k01i += cp * ivi;
                    k10r += qb * ivr; k10i += qb * ivi;
                    k11r += qp * ivr; k11i += qp * ivi;
                }
                float t1r = 1.0f + k11r, t1i = k11i;
                float t2r = k01r * t1r - k01i * t1i;
                float t2i = k01r * t1i + k01i * t1r;
                float t3r = t2r * k10r - t2i * k10i;
                float t3i = t2r * k10i + t2i * k10r;
                float nr = k00r - t3r, ni = k00i - t3i;
                lds[k] = make_float2(cr * nr - ci * ni, cr * ni + ci * nr);
            }
        }
        __syncthreads();

        // phase 1: icfft_2048 input pack, IN PLACE (register-staged reads).
        float2 hm[4], hc[4];
#pragma unroll
        for (int r = 0; r < 4; ++r) {
            int m = tid + (r << 9);              // m < 2048
            hm[r] = lds[m];
            hc[r] = lds[2048 - m];
        }
        __syncthreads();
#pragma unroll
        for (int r = 0; r < 4; ++r) {
            int m = tid + (r << 9);
            float pr = hm[r].x + hc[r].x, pi2 = hm[r].y - hc[r].y;
            float dr = hm[r].x - hc[r].x, di = hm[r].y + hc[r].y;
            float sn, cs;
            __sincosf((float)(3.141592653589793 / 2048.0) * (float)m, &sn, &cs);
            float Or = 0.5f * (cs * dr - sn * di);
            float Oi = 0.5f * (sn * dr + cs * di);
            lds[SZ(m)] = make_float2(0.5f * pr - Oi, -(0.5f * pi2 + Or));
        }
        __syncthreads();

        stage4<2048, 1,   512>(lds, tid);
        stage8<2048, 4,   512>(lds, tid);
        stage8<2048, 32,  512>(lds, tid);
        stage8<2048, 256, 512>(lds, tid);

        // v-pack: conj/2048, zero-pad top half
        const float s1 = 1.0f / 2048.0f;
#pragma unroll
        for (int r = 0; r < 4; ++r) {
            int n = tid + (r << 9);
            float2 o = lds[SZ(n)];
            lds[SZ(n)]        = make_float2(o.x * s1, -o.y * s1);
            lds[SZ(n + 2048)] = make_float2(0.f, 0.f);
        }
        __syncthreads();

        stage8<4096, 1,   512>(lds, tid);
        stage8<4096, 8,   512>(lds, tid);
        stage8<4096, 64,  512>(lds, tid);
        stage8<4096, 512, 512>(lds, tid);

        // untwist -> Kf
        float2* Kfrow = g_Kf + (size_t)i * NBIN2;
#pragma unroll
        for (int r = 0; r < 9; ++r) {
            int m = tid + (r << 9);
            if (m <= 4096) {
                float2 Zq = lds[SZ(m & 4095)];
                float2 Zr = lds[SZ((4096 - m) & 4095)];
                float sn, cs;
                __sincosf((float)(-3.141592653589793 / 4096.0) * (float)m, &sn, &cs);
                float pr = Zq.x + Zr.x, pi2 = Zq.y - Zr.y;
                float dr = Zq.x - Zr.x, di = Zq.y + Zr.y;
                float jt_r = -sn * dr - cs * di;
                float jt_i =  cs * dr - sn * di;
                Kfrow[m] = make_float2(0.5f * (pr - jt_r), 0.5f * (pi2 - jt_i));
            }
        }
    } else {
        // ------------------- forward-FFT path -------------------
        const int blk = blockIdx.x - I_DIM;      // 0..1023
        const int b = blk & 7;                   // batch -> XCD affinity
        const int i = blk >> 3;

        const float* xb = x + (size_t)b * SEQ * I_DIM + i;
#pragma unroll
        for (int r = 0; r < 4; ++r) {
            int n = tid + (r << 9);              // n < 2048 (no zero-fill!)
            float re = xb[(size_t)(2 * n) * I_DIM];
            float im = xb[(size_t)(2 * n + 1) * I_DIM];
            lds[SZ(n)] = make_float2(re, im);
        }
        __syncthreads();

        stage8_first_halfzero(lds, tid);         // exploits zero top half
        stage8<4096, 8,   512>(lds, tid);
        stage8<4096, 64,  512>(lds, tid);
        stage8<4096, 512, 512>(lds, tid);

        float2* dst = g_Xf + (size_t)blk * SEQ;
#pragma unroll
        for (int r = 0; r < 8; ++r) {
            int n = tid + (r << 9);
            dst[n] = lds[SZ(n)];                 // coalesced 8B stores
        }
    }
}

// ===========================================================================
// Kernel 2: load Xf -> combine with Kf -> inverse cfft4096 (conj trick,
// pruned last stage) -> unpack -> y.
// ===========================================================================
__global__ __launch_bounds__(512) void s4_stage2_kernel(float* __restrict__ y) {
    __shared__ float2 lds[4096];
    const int tid = threadIdx.x;
    const int blk = blockIdx.x;
    const int b = blk & 7;
    const int i = blk >> 3;

    const float2* src = g_Xf + (size_t)blk * SEQ;
#pragma unroll
    for (int r = 0; r < 8; ++r) {
        int n = tid + (r << 9);
        lds[SZ(n)] = src[n];                     // coalesced 8B loads
    }
    __syncthreads();

    const float2* Kfrow = g_Kf + (size_t)i * NBIN2;
#pragma unroll
    for (int r = 0; r < 4; ++r) {
        int m = tid + (r << 9);                  // 0..2047
        combine_pair(lds, Kfrow, m, m != 0);
    }
    if (tid == 0)
        combine_pair(lds, Kfrow, 2048, false);   // self-paired Nyquist bin
    __syncthreads();

    stage8<4096, 1,  512>(lds, tid);
    stage8<4096, 8,  512>(lds, tid);
    stage8<4096, 64, 512>(lds, tid);
    stage8_last_half(lds, tid);                  // only n<2048 needed

    const float inv = 1.0f / 4096.0f;
    float* yb = y + (size_t)b * SEQ * I_DIM + i;
#pragma unroll
    for (int r = 0; r < 4; ++r) {
        int n = tid + (r << 9);                  // n < 2048
        float2 v = lds[SZ(n)];
        yb[(size_t)(2 * n) * I_DIM]     = v.x * inv;
        yb[(size_t)(2 * n + 1) * I_DIM] = -v.y * inv;
    }
}

// ---------------------------------------------------------------------------
extern "C" void kernel_launch(void* const* d_in, const int* in_sizes, int n_in,
                              void* d_out, int out_size, void* d_ws, size_t ws_size,
                              hipStream_t stream) {
    const float* x  = (const float*)d_in[0];
    const float* Bm = (const float*)d_in[1];
    const float* Cm = (const float*)d_in[2];
    const float* Lm = (const float*)d_in[3];
    const float* Pm = (const float*)d_in[4];
    const float* Qm = (const float*)d_in[5];
    float* out = (float*)d_out;

    s4_stage1_kernel<<<I_DIM + BATCH * I_DIM, 512, 0, stream>>>(x, Bm, Cm, Lm, Pm, Qm);
    s4_stage2_kernel<<<BATCH * I_DIM, 512, 0, stream>>>(out);
}